// Round 12
// baseline (472.365 us; speedup 1.0000x reference)
//
#include <hip/hip_runtime.h>
#include <stdint.h>

// Problem constants
#define B_    8
#define T_    4096
#define HID   512
#define SD    256
#define NH    8
#define HD    32
#define M_TOK (B_*T_)          // 32768 tokens
#define NPROJ 1536             // 6 * 256 output channels (k,v,q,beta,alpha,gate)

typedef __attribute__((ext_vector_type(8))) short short8;   // 8 bf16 (4 VGPRs) — MFMA A/B frag
typedef __attribute__((ext_vector_type(4))) float f32x4;    // MFMA C/D frag
typedef __attribute__((ext_vector_type(4))) float f4;       // asm ds_read_b128 dst / reg-tuple asm operand
typedef __attribute__((ext_vector_type(2))) float f2;       // packed fp32 (v_pk_*_f32)

__device__ __forceinline__ unsigned short f2bf(float f) {
  uint32_t u = __float_as_uint(f);
  uint32_t r = (u + 0x7fffu + ((u >> 16) & 1u)) >> 16;
  return (unsigned short)r;
}

__device__ __forceinline__ void gload16(const void* g, void* l) {
  // async global->LDS, 16B per lane; LDS dest = wave-uniform base + lane*16
  __builtin_amdgcn_global_load_lds((const __attribute__((address_space(1))) void*)g,
                                   (__attribute__((address_space(3))) void*)l,
                                   16, 0, 0);
}

// butterfly sum across 16 consecutive lanes — pure VALU (DPP), no DS pipe.
__device__ __forceinline__ float qred16(float x) {
  x += __int_as_float(__builtin_amdgcn_mov_dpp(__float_as_int(x), 0xB1,  0xF, 0xF, true));
  x += __int_as_float(__builtin_amdgcn_mov_dpp(__float_as_int(x), 0x4E,  0xF, 0xF, true));
  x += __int_as_float(__builtin_amdgcn_mov_dpp(__float_as_int(x), 0x141, 0xF, 0xF, true));
  x += __int_as_float(__builtin_amdgcn_mov_dpp(__float_as_int(x), 0x128, 0xF, 0xF, true));
  return x;
}

// butterfly sum across 8 consecutive lanes — 3 DPP levels (xor1, xor2, half-mirror)
__device__ __forceinline__ float qred8(float x) {
  x += __int_as_float(__builtin_amdgcn_mov_dpp(__float_as_int(x), 0xB1,  0xF, 0xF, true));
  x += __int_as_float(__builtin_amdgcn_mov_dpp(__float_as_int(x), 0x4E,  0xF, 0xF, true));
  x += __int_as_float(__builtin_amdgcn_mov_dpp(__float_as_int(x), 0x141, 0xF, 0xF, true));
  return x;
}

// quad broadcasts (value of lane base+j in every lane of the quad)
__device__ __forceinline__ float dpp_b1(float x) {
  return __int_as_float(__builtin_amdgcn_mov_dpp(__float_as_int(x), 0x55, 0xF, 0xF, true));
}
__device__ __forceinline__ float dpp_b2(float x) {
  return __int_as_float(__builtin_amdgcn_mov_dpp(__float_as_int(x), 0xAA, 0xF, 0xF, true));
}
__device__ __forceinline__ float dpp_b3(float x) {
  return __int_as_float(__builtin_amdgcn_mov_dpp(__float_as_int(x), 0xFF, 0xF, 0xF, true));
}

// ---------------------------------------------------------------- converts
__global__ void cvt_f32_bf16(const float* __restrict__ in, unsigned short* __restrict__ out, int n4) {
  int i = blockIdx.x * blockDim.x + threadIdx.x;
  int stride = gridDim.x * blockDim.x;
  for (; i < n4; i += stride) {
    float4 v = reinterpret_cast<const float4*>(in)[i];
    ushort4 o;
    o.x = f2bf(v.x); o.y = f2bf(v.y); o.z = f2bf(v.z); o.w = f2bf(v.w);
    reinterpret_cast<ushort4*>(out)[i] = o;
  }
}

// ---------------------------------------------------------------- projection GEMM (fused 3-way)
// grid (256, 8): role 0-3: col-tile of {k, q, gate}; role 4-7: {alpha, v, beta}.
// KQi layout: [tok][8 groups g][k(4g..4g+3) , q(4g..4g+3)]  (32B per group).
// Epilogue gathers each quad's 4 k (and q) values via quad_perm broadcasts and
// stores FULL 16B f4s (no partial sectors). k-normalization fused.
#define PM 128
#define PN 64
#define PK 64

__global__ void __launch_bounds__(256) proj_gemm(
    const unsigned short* __restrict__ hb, const unsigned short* __restrict__ Wc,
    const float* __restrict__ b_beta, const float* __restrict__ b_alpha,
    float* __restrict__ KQi, float* __restrict__ AVBf, float* __restrict__ gate)
{
  __shared__ unsigned short Asm[PM*PK];      // 16 KB
  __shared__ unsigned short Bsm[3][PN*PK];   // 24 KB
  const int t = threadIdx.x;
  const int w = t >> 6, lane = t & 63;
  const int bm0 = blockIdx.x * PM;
  const int role = blockIdx.y;
  const int grp = role >> 2;       // 0 = {k,q,gate}, 1 = {alpha,v,beta}
  const int bn0 = (role & 3) * 64; // column offset within each projection (0..255)
  const int pr0 = grp ? 4 : 0, pr1 = grp ? 1 : 2, pr2 = grp ? 3 : 5;

  f32x4 acc[3][2][4];
  #pragma unroll
  for (int pp = 0; pp < 3; ++pp)
    #pragma unroll
    for (int i = 0; i < 2; ++i)
      #pragma unroll
      for (int j = 0; j < 4; ++j) acc[pp][i][j] = (f32x4){0.f, 0.f, 0.f, 0.f};

  for (int k0 = 0; k0 < HID; k0 += PK) {
    #pragma unroll
    for (int it = 0; it < 4; ++it) {
      int unit = t + it * 256;
      int row = unit >> 3, seg = unit & 7;
      int dseg = seg ^ (row & 7);
      const unsigned short* g = hb + (size_t)(bm0 + row) * HID + k0 + dseg * 8;
      gload16(g, (char*)Asm + (w * 1024 + it * 4096));
    }
    #pragma unroll
    for (int pp = 0; pp < 3; ++pp) {
      const int pr = (pp == 0) ? pr0 : (pp == 1) ? pr1 : pr2;
      #pragma unroll
      for (int it = 0; it < 2; ++it) {
        int unit = t + it * 256;
        int n = unit >> 3, seg = unit & 7;
        int dseg = seg ^ (n & 7);
        const unsigned short* g = Wc + (size_t)(pr * 256 + bn0 + n) * HID + k0 + dseg * 8;
        gload16(g, (char*)Bsm[pp] + (w * 1024 + it * 4096));
      }
    }
    __syncthreads();
    #pragma unroll
    for (int ks = 0; ks < 2; ++ks) {
      short8 af[2];
      int u = ks * 4 + (lane >> 4);
      int slot = u ^ (lane & 7);
      #pragma unroll
      for (int rb = 0; rb < 2; ++rb) {
        int row = w * 32 + rb * 16 + (lane & 15);
        af[rb] = *(const short8*)((const char*)Asm + row * 128 + slot * 16);
      }
      #pragma unroll
      for (int pp = 0; pp < 3; ++pp) {
        short8 bfr[4];
        #pragma unroll
        for (int cb = 0; cb < 4; ++cb) {
          int nn = cb * 16 + (lane & 15);
          bfr[cb] = *(const short8*)((const char*)Bsm[pp] + nn * 128 + slot * 16);
        }
        #pragma unroll
        for (int rb = 0; rb < 2; ++rb)
          #pragma unroll
          for (int cb = 0; cb < 4; ++cb)
            acc[pp][rb][cb] = __builtin_amdgcn_mfma_f32_16x16x32_bf16(af[rb], bfr[cb], acc[pp][rb][cb], 0, 0, 0);
      }
    }
    __syncthreads();
  }

  if (grp == 0) {
    // fused k-normalization (16-lane DPP row covers all 32 d of one (m,h))
    #pragma unroll
    for (int rb = 0; rb < 2; ++rb) {
      #pragma unroll
      for (int r = 0; r < 4; ++r) {
        float s0 = acc[0][rb][0][r] * acc[0][rb][0][r] + acc[0][rb][1][r] * acc[0][rb][1][r];
        float s1 = acc[0][rb][2][r] * acc[0][rb][2][r] + acc[0][rb][3][r] * acc[0][rb][3][r];
        s0 = qred16(s0); s1 = qred16(s1);
        float i0 = 1.0f / fmaxf(sqrtf(s0), 1e-12f);
        float i1 = 1.0f / fmaxf(sqrtf(s1), 1e-12f);
        acc[0][rb][0][r] *= i0; acc[0][rb][1][r] *= i0;
        acc[0][rb][2][r] *= i1; acc[0][rb][3][r] *= i1;
      }
    }
    #pragma unroll
    for (int rb = 0; rb < 2; ++rb) {
      #pragma unroll
      for (int cb = 0; cb < 4; ++cb) {
        int rem = bn0 + cb * 16 + (lane & 15);
        int h = rem >> 5, d = rem & 31;   // d&3 == lane&3
        #pragma unroll
        for (int r = 0; r < 4; ++r) {
          int m = bm0 + w * 32 + rb * 16 + (lane >> 4) * 4 + r;
          int bb = m >> 12, tt = m & 4095;
          size_t tok = ((size_t)(bb * NH + h) * T_ + tt);
          float kv = acc[0][rb][cb][r], qv = acc[1][rb][cb][r];
          f4 kp = (f4){kv, dpp_b1(kv), dpp_b2(kv), dpp_b3(kv)};
          f4 qp = (f4){qv, dpp_b1(qv), dpp_b2(qv), dpp_b3(qv)};
          // ext_vector_type -> register-tuple asm operand (HIP float4 is a
          // struct => indirect operand => unsupported tied asm input)
          asm volatile("" : "+v"(kp), "+v"(qp));   // pin DPP eval before branch
          if ((lane & 3) == 0) {
            *(f4*)&KQi[tok * 64 + (d >> 2) * 8]     = kp;
            *(f4*)&KQi[tok * 64 + (d >> 2) * 8 + 4] = qp;
          }
          gate[(size_t)m * SD + rem] = acc[2][rb][cb][r];
        }
      }
    }
  } else {
    #pragma unroll
    for (int rb = 0; rb < 2; ++rb) {
      #pragma unroll
      for (int cb = 0; cb < 4; ++cb) {
        int rem = bn0 + cb * 16 + (lane & 15);
        int h = rem >> 5, d = rem & 31;
        #pragma unroll
        for (int r = 0; r < 4; ++r) {
          int m = bm0 + w * 32 + rb * 16 + (lane >> 4) * 4 + r;
          int bb = m >> 12, tt = m & 4095;
          size_t tok = ((size_t)(bb * NH + h) * T_ + tt);
          float av = 1.0f / (1.0f + expf(-(acc[0][rb][cb][r] + b_alpha[rem])));
          float vv = acc[1][rb][cb][r];
          float bv = 1.0f / (1.0f + expf(-(acc[2][rb][cb][r] + b_beta[rem])));
          *(float4*)&AVBf[(tok * HD + d) * 4] = (float4){av, vv, bv, 0.0f};
        }
      }
    }
  }
}

// ---------------------------------------------------------------- sequential scan
// 256 blocks x 128 threads (1 block/CU). block = (rg, bh): bh = blk&63, rg = blk>>6
// (4 row-groups of 8 rows). WAVE0: lane = row il (lw>>3) x part p (lw&7); 4 cols
// per lane (2 f2). In-chain reduce = qred8 (3 DPP levels). Per step: 3 ds_read_b128
// (k, q, AVB) + 1 ds_write_b32 partial to ring. Depth-4 register pipeline; exact
// lgkm schedule: prologue 9/10/11, steady 12, tail 12/9/6/3 (4 lgkm ops/step).
// WAVE1: stages chunks (KQ 8KB + AVB 4KB per buf) via global_load_lds, vmcnt(0)
// before chunk-boundary barriers; REDUCE: lane (il1=lw>>3, tq=lw&7) sums 8 parts
// for steps tq and tq+8 of a 16-step ring buffer (272B/step pad) -> 2 ctx stores.
// LDS: KQ dbuf 16KB @0, AVB dbuf 8KB @16384, ring 4x4352B @24576 = 41984 B.
#define CH 32
#define NCH (T_/CH)
#define RING 24576

#define DSR(dst, areg, imm) \
  asm volatile("ds_read_b128 %0, %1 offset:%c2" : "=v"(dst) : "v"(areg), "i"(imm))

#define SHUF2(V,A,B) __builtin_shufflevector(V, V, A, B)

#define BAR asm volatile("s_barrier" ::: "memory")

__global__ void __launch_bounds__(128, 1) scan_kernel(
    const float* __restrict__ KQi, const float4* __restrict__ AVB,
    const float* __restrict__ state_in,
    float* __restrict__ ctx, float* __restrict__ Sfin)
{
  __shared__ __align__(16) char Lds[41984];
  const int blk = blockIdx.x;
  const int bh = blk & 63, rg = blk >> 6;       // rg 0..3
  const int b = bh >> 3, h = bh & 7;
  const int tid = threadIdx.x;
  const int wid = tid >> 6;
  const int lw = tid & 63;

  const float*  KQg = KQi + (size_t)bh * (T_ * 64);
  const float4* Vg  = AVB + (size_t)bh * (T_ * HD) + rg * 8;

  const uint32_t lds0 = (uint32_t)(uintptr_t)(__attribute__((address_space(3))) char*)&Lds[0];

  if (wid == 1) {
    // ---------------- WAVE1: producer (staging) + readout reducer ----------------
    const int il1 = lw >> 3, tq = lw & 7;
    const uint32_t a_pr = lds0 + RING + tq * 272 + il1 * 32;
    float* ctxb = ctx + (size_t)b * T_ * SD + h * HD + rg * 8 + il1;

    auto stageW = [&](int c2, int buf) {
      const float* kqg = KQg + (size_t)c2 * (CH * 64);
      #pragma unroll
      for (int it = 0; it < 8; ++it)
        gload16(kqg + (size_t)(lw + it * 64) * 4, Lds + buf * 8192 + it * 1024);
      const float4* vg = Vg + (size_t)c2 * (CH * HD);
      #pragma unroll
      for (int it = 0; it < 4; ++it) {
        int tt = it * 8 + (lw >> 3), rr = lw & 7;
        gload16(vg + (size_t)tt * HD + rr, Lds + 16384 + buf * 4096 + it * 1024);
      }
    };

#define REDUCE(PB, T0) do { \
      f4 r0_, r1_, r2_, r3_; \
      DSR(r0_, a_pr, (PB)*4352 + 0);    DSR(r1_, a_pr, (PB)*4352 + 16); \
      DSR(r2_, a_pr, (PB)*4352 + 2176); DSR(r3_, a_pr, (PB)*4352 + 2192); \
      asm volatile("s_waitcnt lgkmcnt(0)" : "+v"(r0_), "+v"(r1_), "+v"(r2_), "+v"(r3_)); \
      f4 sA_ = r0_ + r1_, sB_ = r2_ + r3_; \
      float vA_ = (sA_.x + sA_.y) + (sA_.z + sA_.w); \
      float vB_ = (sB_.x + sB_.y) + (sB_.z + sB_.w); \
      ctxb[(size_t)((T0) + tq) * SD] = vA_; \
      ctxb[(size_t)((T0) + tq + 8) * SD] = vB_; \
    } while (0)

    stageW(0, 0);
    asm volatile("s_waitcnt vmcnt(0)" ::: "memory");
    BAR;   // prologue: chunk 0 staged
    #pragma unroll 1
    for (int cp = 0; cp < NCH / 2; ++cp) {
      if (cp > 0) REDUCE(2, 64 * cp - 32);
      stageW(2 * cp + 1, 1);
      BAR;
      if (cp > 0) REDUCE(3, 64 * cp - 16);
      asm volatile("s_waitcnt vmcnt(0)" ::: "memory");
      BAR;
      REDUCE(0, 64 * cp);
      if (cp < NCH / 2 - 1) stageW(2 * cp + 2, 0);
      BAR;
      REDUCE(1, 64 * cp + 16);
      asm volatile("s_waitcnt vmcnt(0)" ::: "memory");
      BAR;
    }
    BAR;  // final sync (wave0 drained its last partial writes)
    REDUCE(2, T_ - 32);
    REDUCE(3, T_ - 16);
#undef REDUCE
    return;
  }

  // ---------------- WAVE0: the sequential recurrence ----------------
  const int il = lw >> 3;    // local row 0..7 (global row rg*8+il)
  const int p  = lw & 7;     // column part (cols 4p..4p+3)

  f2 S01, S23;
  {
    const float* sp = state_in + (size_t)bh * 1024 + (rg * 8 + il) * 32 + p * 4;
    float4 s0 = *(const float4*)sp;
    S01 = (f2){s0.x, s0.y}; S23 = (f2){s0.z, s0.w};
  }

  const uint32_t a_kq = lds0 + p * 32;
  const uint32_t a_v  = lds0 + 16384 + il * 16;
  const uint32_t a_pw = lds0 + RING + lw * 4;

#define C1(S, T, PB) do { \
    f2 kl_ = SHUF2(k##S, 0, 1), kh_ = SHUF2(k##S, 2, 3); \
    f2 ql_ = SHUF2(q##S, 0, 1), qh_ = SHUF2(q##S, 2, 3); \
    f4 VV_ = v##S; \
    f2 A2_ = (f2){VV_.x, VV_.x}; \
    f2 as0_ = A2_ * S01, as1_ = A2_ * S23; \
    f2 d_ = kl_ * S01; d_ = __builtin_elementwise_fma(kh_, S23, d_); \
    float pd_ = qred8(d_.x + d_.y); \
    float bv_ = VV_.y * VV_.z, ba_ = VV_.x * VV_.z; \
    float u_ = fmaf(-ba_, pd_, bv_); \
    f2 U2_ = (f2){u_, u_}; \
    S01 = __builtin_elementwise_fma(U2_, kl_, as0_); \
    S23 = __builtin_elementwise_fma(U2_, kh_, as1_); \
    f2 o_ = ql_ * S01; o_ = __builtin_elementwise_fma(qh_, S23, o_); \
    float po_ = o_.x + o_.y; \
    asm volatile("ds_write_b32 %0, %1 offset:%c2" :: "v"(a_pw), "v"(po_), "i"((PB)*4352 + ((T)&15)*272)); \
  } while (0)

  f4 kA, qA, vA, kB, qB, vB, kC, qC, vC, kD, qD, vD;

#define R1(S, BUF, T) do { \
    DSR(k##S, a_kq, (BUF)*8192 + (T)*256); \
    DSR(q##S, a_kq, (BUF)*8192 + (T)*256 + 16); \
    DSR(v##S, a_v,  (BUF)*4096 + (T)*128); \
  } while (0)

#define WKA(N, S) \
    asm volatile("s_waitcnt lgkmcnt(" #N ")" : "+v"(k##S), "+v"(q##S), "+v"(v##S))

#define CHUNK(BUF, PBa, PBb) do { \
    R1(A,BUF,0); R1(B,BUF,1); R1(C,BUF,2); R1(D,BUF,3); \
    WKA(9 ,A); C1(A, 0,PBa); R1(A,BUF, 4); \
    WKA(10,B); C1(B, 1,PBa); R1(B,BUF, 5); \
    WKA(11,C); C1(C, 2,PBa); R1(C,BUF, 6); \
    WKA(12,D); C1(D, 3,PBa); R1(D,BUF, 7); \
    WKA(12,A); C1(A, 4,PBa); R1(A,BUF, 8); \
    WKA(12,B); C1(B, 5,PBa); R1(B,BUF, 9); \
    WKA(12,C); C1(C, 6,PBa); R1(C,BUF,10); \
    WKA(12,D); C1(D, 7,PBa); R1(D,BUF,11); \
    WKA(12,A); C1(A, 8,PBa); R1(A,BUF,12); \
    WKA(12,B); C1(B, 9,PBa); R1(B,BUF,13); \
    WKA(12,C); C1(C,10,PBa); R1(C,BUF,14); \
    WKA(12,D); C1(D,11,PBa); R1(D,BUF,15); \
    WKA(12,A); C1(A,12,PBa); R1(A,BUF,16); \
    WKA(12,B); C1(B,13,PBa); R1(B,BUF,17); \
    WKA(12,C); C1(C,14,PBa); R1(C,BUF,18); \
    WKA(12,D); C1(D,15,PBa); R1(D,BUF,19); \
    BAR; \
    WKA(12,A); C1(A,16,PBb); R1(A,BUF,20); \
    WKA(12,B); C1(B,17,PBb); R1(B,BUF,21); \
    WKA(12,C); C1(C,18,PBb); R1(C,BUF,22); \
    WKA(12,D); C1(D,19,PBb); R1(D,BUF,23); \
    WKA(12,A); C1(A,20,PBb); R1(A,BUF,24); \
    WKA(12,B); C1(B,21,PBb); R1(B,BUF,25); \
    WKA(12,C); C1(C,22,PBb); R1(C,BUF,26); \
    WKA(12,D); C1(D,23,PBb); R1(D,BUF,27); \
    WKA(12,A); C1(A,24,PBb); R1(A,BUF,28); \
    WKA(12,B); C1(B,25,PBb); R1(B,BUF,29); \
    WKA(12,C); C1(C,26,PBb); R1(C,BUF,30); \
    WKA(12,D); C1(D,27,PBb); R1(D,BUF,31); \
    WKA(12,A); C1(A,28,PBb); \
    WKA(9 ,B); C1(B,29,PBb); \
    WKA(6 ,C); C1(C,30,PBb); \
    WKA(3 ,D); C1(D,31,PBb); \
    BAR; \
  } while (0)

  BAR;   // prologue: wait for wave1's stage(0)
  #pragma unroll 1
  for (int cp = 0; cp < NCH / 2; ++cp) {
    CHUNK(0, 0, 1);
    CHUNK(1, 2, 3);
  }
  asm volatile("s_waitcnt lgkmcnt(0)" ::: "memory");
  BAR;   // final: partial writes of last group retired/visible

  {
    float* sp = Sfin + (size_t)bh * 1024 + (rg * 8 + il) * 32 + p * 4;
    *(float4*)sp = (float4){S01.x, S01.y, S23.x, S23.y};
  }
#undef C1
#undef R1
#undef WKA
#undef CHUNK
}

// ---------------------------------------------------------------- rmsnorm * silu(gate) -> bf16
__global__ void __launch_bounds__(256) rms_silu(
    const float* __restrict__ ctx, const float* __restrict__ gate,
    const float* __restrict__ norm_w, unsigned short* __restrict__ ctx2)
{
  size_t row = (size_t)blockIdx.x * 4 + (threadIdx.x >> 6);
  int lane = threadIdx.x & 63;
  const float4 x = *(const float4*)&ctx[row * SD + lane * 4];
  float s = x.x * x.x + x.y * x.y + x.z * x.z + x.w * x.w;
  #pragma unroll
  for (int m = 32; m >= 1; m >>= 1) s += __shfl_xor(s, m, 64);
  float rs = 1.0f / sqrtf(s * (1.0f / 256.0f) + 1e-6f);
  const float4 g = *(const float4*)&gate[row * SD + lane * 4];
  const float4 w = *(const float4*)&norm_w[lane * 4];
  ushort4 o;
  o.x = f2bf(x.x * rs * w.x * (g.x / (1.0f + expf(-g.x))));
  o.y = f2bf(x.y * rs * w.y * (g.y / (1.0f + expf(-g.y))));
  o.z = f2bf(x.z * rs * w.z * (g.z / (1.0f + expf(-g.z))));
  o.w = f2bf(x.w * rs * w.w * (g.w / (1.0f + expf(-g.w))));
  *(ushort4*)&ctx2[row * SD + lane * 4] = o;
}

// ---------------------------------------------------------------- output GEMM
__global__ void __launch_bounds__(256) out_gemm(
    const unsigned short* __restrict__ ctx2, const unsigned short* __restrict__ Wob,
    float* __restrict__ out)
{
  __shared__ unsigned short Asm[PM*PK];
  __shared__ unsigned short Bsm[PN*PK];
  const int t = threadIdx.x;
  const int w = t >> 6, lane = t & 63;
  const int bm0 = blockIdx.x * PM;
  const int bn0 = blockIdx.y * PN;

  f32x4 acc[2][4];
  #pragma unroll
  for (int i = 0; i < 2; ++i)
    #pragma unroll
    for (int j = 0; j < 4; ++j) acc[i][j] = (f32x4){0.f, 0.f, 0.f, 0.f};

  for (int k0 = 0; k0 < SD; k0 += PK) {
    #pragma unroll
    for (int it = 0; it < 4; ++it) {
      int unit = t + it * 256;
      int row = unit >> 3, seg = unit & 7;
      int dseg = seg ^ (row & 7);
      const unsigned short* g = ctx2 + (size_t)(bm0 + row) * SD + k0 + dseg * 8;
      gload16(g, (char*)Asm + (w * 1024 + it * 4096));
    }
    #pragma unroll
    for (int it = 0; it < 2; ++it) {
      int unit = t + it * 256;
      int n = unit >> 3, seg = unit & 7;
      int dseg = seg ^ (n & 7);
      const unsigned short* g = Wob + (size_t)(bn0 + n) * SD + k0 + dseg * 8;
      gload16(g, (char*)Bsm + (w * 1024 + it * 4096));
    }
    __syncthreads();
    #pragma unroll
    for (int ks = 0; ks < 2; ++ks) {
      short8 af[2], bfr[4];
      int u = ks * 4 + (lane >> 4);
      int slot = u ^ (lane & 7);
      #pragma unroll
      for (int rb = 0; rb < 2; ++rb) {
        int row = w * 32 + rb * 16 + (lane & 15);
        af[rb] = *(const short8*)((const char*)Asm + row * 128 + slot * 16);
      }
      #pragma unroll
      for (int cb = 0; cb < 4; ++cb) {
        int nn = cb * 16 + (lane & 15);
        bfr[cb] = *(const short8*)((const char*)Bsm + nn * 128 + slot * 16);
      }
      #pragma unroll
      for (int rb = 0; rb < 2; ++rb)
        #pragma unroll
        for (int cb = 0; cb < 4; ++cb)
          acc[rb][cb] = __builtin_amdgcn_mfma_f32_16x16x32_bf16(af[rb], bfr[cb], acc[rb][cb], 0, 0, 0);
    }
    __syncthreads();
  }
  #pragma unroll
  for (int rb = 0; rb < 2; ++rb)
    #pragma unroll
    for (int cb = 0; cb < 4; ++cb) {
      int n = bn0 + cb * 16 + (lane & 15);
      #pragma unroll
      for (int r = 0; r < 4; ++r) {
        int m = bm0 + w * 32 + rb * 16 + (lane >> 4) * 4 + r;
        out[(size_t)m * 512 + n] = acc[rb][cb][r];
      }
    }
}

// ---------------------------------------------------------------- launcher
// ws layout (bytes), total 253,493,248:
//   hb   bf16 [32768][512]            @ 0
//   Wc   bf16 [1536][512]             @ 33,554,432
//   Wob  bf16 [512][256]              @ 35,127,296
//   KQi  f32  [64][4096][64]          @ 35,389,440   (8 groups x [k4, q4])
//   AVB  f32x4 [64][4096][32]         @ 102,498,304  (a, v, beta, pad)
//   ctx2 bf16 [32768][256]            @ 236,716,032
// d_out reuse: ctx f32 [32768][256] @ 0; gate f32 [32768][256] @ +8388608 floats
// (both overwritten later by out_gemm); Sfin @ +16777216 floats.
extern "C" void kernel_launch(void* const* d_in, const int* in_sizes, int n_in,
                              void* d_out, int out_size, void* d_ws, size_t ws_size,
                              hipStream_t stream) {
  (void)in_sizes; (void)n_in; (void)out_size; (void)ws_size;
  const float* hidden  = (const float*)d_in[0];
  const float* state   = (const float*)d_in[1];
  const float* W_k     = (const float*)d_in[2];
  const float* W_v     = (const float*)d_in[3];
  const float* W_q     = (const float*)d_in[4];
  const float* W_beta  = (const float*)d_in[5];
  const float* b_beta  = (const float*)d_in[6];
  const float* W_alpha = (const float*)d_in[7];
  const float* b_alpha = (const float*)d_in[8];
  const float* W_out   = (const float*)d_in[9];
  const float* gate_W  = (const float*)d_in[10];
  const float* norm_w  = (const float*)d_in[11];
  float* out = (float*)d_out;

  char* ws = (char*)d_ws;
  unsigned short* hb  = (unsigned short*)(ws);
  unsigned short* Wc  = (unsigned short*)(ws + 33554432);
  unsigned short* Wob = (unsigned short*)(ws + 35127296);
  float* KQi  = (float*)(ws + 35389440);
  float* AVBf = (float*)(ws + 102498304);
  unsigned short* ctx2 = (unsigned short*)(ws + 236716032);
  float* ctx  = out;                 // fp32 scratch, overwritten by out_gemm
  float* gate = out + 8388608;       // fp32 scratch, overwritten by out_gemm
  float* Sfin = out + 16777216;      // final state output

  cvt_f32_bf16<<<2048, 256, 0, stream>>>(hidden, hb, M_TOK * HID / 4);
  cvt_f32_bf16<<<64, 256, 0, stream>>>(W_k,     Wc + 0 * 131072, 32768);
  cvt_f32_bf16<<<64, 256, 0, stream>>>(W_v,     Wc + 1 * 131072, 32768);
  cvt_f32_bf16<<<64, 256, 0, stream>>>(W_q,     Wc + 2 * 131072, 32768);
  cvt_f32_bf16<<<64, 256, 0, stream>>>(W_beta,  Wc + 3 * 131072, 32768);
  cvt_f32_bf16<<<64, 256, 0, stream>>>(W_alpha, Wc + 4 * 131072, 32768);
  cvt_f32_bf16<<<64, 256, 0, stream>>>(gate_W,  Wc + 5 * 131072, 32768);
  cvt_f32_bf16<<<64, 256, 0, stream>>>(W_out,   Wob, 32768);

  proj_gemm<<<dim3(256, 8), 256, 0, stream>>>(hb, Wc, b_beta, b_alpha, KQi, AVBf, gate);
  scan_kernel<<<256, 128, 0, stream>>>(KQi, (const float4*)AVBf, state, ctx, Sfin);
  rms_silu<<<8192, 256, 0, stream>>>(ctx, gate, norm_w, ctx2);
  out_gemm<<<dim3(256, 8), 256, 0, stream>>>(ctx2, Wob, out);
}

// Round 13
// 432.394 us; speedup vs baseline: 1.0924x; 1.0924x over previous
//
#include <hip/hip_runtime.h>
#include <stdint.h>

// Problem constants
#define B_    8
#define T_    4096
#define HID   512
#define SD    256
#define NH    8
#define HD    32
#define M_TOK (B_*T_)          // 32768 tokens

typedef __attribute__((ext_vector_type(8))) short short8;   // 8 bf16 (4 VGPRs) — MFMA A/B frag
typedef __attribute__((ext_vector_type(4))) float f32x4;    // MFMA C/D frag
typedef __attribute__((ext_vector_type(4))) float f4;       // reg-tuple 4xf32 (asm-safe)
typedef __attribute__((ext_vector_type(2))) float f2;       // packed fp32 (v_pk_*_f32)

__device__ __forceinline__ unsigned short f2bf(float f) {
  uint32_t u = __float_as_uint(f);
  uint32_t r = (u + 0x7fffu + ((u >> 16) & 1u)) >> 16;
  return (unsigned short)r;
}

__device__ __forceinline__ void gload16(const void* g, void* l) {
  // async global->LDS, 16B per lane; LDS dest = wave-uniform base + lane*16
  __builtin_amdgcn_global_load_lds((const __attribute__((address_space(1))) void*)g,
                                   (__attribute__((address_space(3))) void*)l,
                                   16, 0, 0);
}

// butterfly sum across 16 consecutive lanes — pure VALU (DPP), no DS pipe.
__device__ __forceinline__ float qred16(float x) {
  x += __int_as_float(__builtin_amdgcn_mov_dpp(__float_as_int(x), 0xB1,  0xF, 0xF, true));
  x += __int_as_float(__builtin_amdgcn_mov_dpp(__float_as_int(x), 0x4E,  0xF, 0xF, true));
  x += __int_as_float(__builtin_amdgcn_mov_dpp(__float_as_int(x), 0x141, 0xF, 0xF, true));
  x += __int_as_float(__builtin_amdgcn_mov_dpp(__float_as_int(x), 0x128, 0xF, 0xF, true));
  return x;
}

// value of lane^1 (quad_perm [1,0,3,2]) — pure VALU
__device__ __forceinline__ float dpp_xor1(float x) {
  return __int_as_float(__builtin_amdgcn_mov_dpp(__float_as_int(x), 0xB1, 0xF, 0xF, true));
}

// ---------------------------------------------------------------- converts
__global__ void cvt_f32_bf16(const float* __restrict__ in, unsigned short* __restrict__ out, int n4) {
  int i = blockIdx.x * blockDim.x + threadIdx.x;
  int stride = gridDim.x * blockDim.x;
  for (; i < n4; i += stride) {
    float4 v = reinterpret_cast<const float4*>(in)[i];
    ushort4 o;
    o.x = f2bf(v.x); o.y = f2bf(v.y); o.z = f2bf(v.z); o.w = f2bf(v.w);
    reinterpret_cast<ushort4*>(out)[i] = o;
  }
}

// all 7 weight matrices in one launch: grid (128, 7), 32768 float4 per slice
__global__ void __launch_bounds__(256) cvt_weights(
    const float* __restrict__ W_k, const float* __restrict__ W_v,
    const float* __restrict__ W_q, const float* __restrict__ W_beta,
    const float* __restrict__ W_alpha, const float* __restrict__ gate_W,
    const float* __restrict__ W_out,
    unsigned short* __restrict__ Wc, unsigned short* __restrict__ Wob)
{
  int slice = blockIdx.y;
  const float* src = (slice == 0) ? W_k : (slice == 1) ? W_v : (slice == 2) ? W_q :
                     (slice == 3) ? W_beta : (slice == 4) ? W_alpha : (slice == 5) ? gate_W : W_out;
  unsigned short* dst = (slice == 6) ? Wob : (Wc + slice * 131072);
  int i = blockIdx.x * 256 + threadIdx.x;   // 0..32767 float4 units
  float4 v = reinterpret_cast<const float4*>(src)[i];
  ushort4 o;
  o.x = f2bf(v.x); o.y = f2bf(v.y); o.z = f2bf(v.z); o.w = f2bf(v.w);
  reinterpret_cast<ushort4*>(dst)[i] = o;
}

// ---------------------------------------------------------------- projection GEMM (fused 3-way)
// grid (256, 8): role 0-3: col-tile of {k, q, gate}; role 4-7: {alpha, v, beta}.
// KQi layout: [tok][16 groups g][k_{2g} k_{2g+1} q_{2g} q_{2g+1}] (16B/group).
// Epilogue writes FULL 16B groups per store (KQi via lane^1 DPP pair-exchange,
// even lanes store float4 {k0,k1,q0,q1}; AVB one float4 {a,v,b,0} per lane).
// k-normalization fused in-register (16-lane qred16 per token-half).
#define PM 128
#define PN 64
#define PK 64

__global__ void __launch_bounds__(256) proj_gemm(
    const unsigned short* __restrict__ hb, const unsigned short* __restrict__ Wc,
    const float* __restrict__ b_beta, const float* __restrict__ b_alpha,
    float* __restrict__ KQi, float* __restrict__ AVBf, float* __restrict__ gate)
{
  __shared__ unsigned short Asm[PM*PK];      // 16 KB
  __shared__ unsigned short Bsm[3][PN*PK];   // 24 KB
  const int t = threadIdx.x;
  const int w = t >> 6, lane = t & 63;
  const int bm0 = blockIdx.x * PM;
  const int role = blockIdx.y;
  const int grp = role >> 2;       // 0 = {k,q,gate}, 1 = {alpha,v,beta}
  const int bn0 = (role & 3) * 64; // column offset within each projection (0..255)
  const int pr0 = grp ? 4 : 0, pr1 = grp ? 1 : 2, pr2 = grp ? 3 : 5;

  f32x4 acc[3][2][4];
  #pragma unroll
  for (int pp = 0; pp < 3; ++pp)
    #pragma unroll
    for (int i = 0; i < 2; ++i)
      #pragma unroll
      for (int j = 0; j < 4; ++j) acc[pp][i][j] = (f32x4){0.f, 0.f, 0.f, 0.f};

  for (int k0 = 0; k0 < HID; k0 += PK) {
    #pragma unroll
    for (int it = 0; it < 4; ++it) {
      int unit = t + it * 256;
      int row = unit >> 3, seg = unit & 7;
      int dseg = seg ^ (row & 7);
      const unsigned short* g = hb + (size_t)(bm0 + row) * HID + k0 + dseg * 8;
      gload16(g, (char*)Asm + (w * 1024 + it * 4096));
    }
    #pragma unroll
    for (int pp = 0; pp < 3; ++pp) {
      const int pr = (pp == 0) ? pr0 : (pp == 1) ? pr1 : pr2;
      #pragma unroll
      for (int it = 0; it < 2; ++it) {
        int unit = t + it * 256;
        int n = unit >> 3, seg = unit & 7;
        int dseg = seg ^ (n & 7);
        const unsigned short* g = Wc + (size_t)(pr * 256 + bn0 + n) * HID + k0 + dseg * 8;
        gload16(g, (char*)Bsm[pp] + (w * 1024 + it * 4096));
      }
    }
    __syncthreads();
    #pragma unroll
    for (int ks = 0; ks < 2; ++ks) {
      short8 af[2];
      int u = ks * 4 + (lane >> 4);
      int slot = u ^ (lane & 7);
      #pragma unroll
      for (int rb = 0; rb < 2; ++rb) {
        int row = w * 32 + rb * 16 + (lane & 15);
        af[rb] = *(const short8*)((const char*)Asm + row * 128 + slot * 16);
      }
      #pragma unroll
      for (int pp = 0; pp < 3; ++pp) {
        short8 bfr[4];
        #pragma unroll
        for (int cb = 0; cb < 4; ++cb) {
          int nn = cb * 16 + (lane & 15);
          bfr[cb] = *(const short8*)((const char*)Bsm[pp] + nn * 128 + slot * 16);
        }
        #pragma unroll
        for (int rb = 0; rb < 2; ++rb)
          #pragma unroll
          for (int cb = 0; cb < 4; ++cb)
            acc[pp][rb][cb] = __builtin_amdgcn_mfma_f32_16x16x32_bf16(af[rb], bfr[cb], acc[pp][rb][cb], 0, 0, 0);
      }
    }
    __syncthreads();
  }

  if (grp == 0) {
    // fused k-normalization (16-lane DPP row covers all 32 d of one (m,h))
    #pragma unroll
    for (int rb = 0; rb < 2; ++rb) {
      #pragma unroll
      for (int r = 0; r < 4; ++r) {
        float s0 = acc[0][rb][0][r] * acc[0][rb][0][r] + acc[0][rb][1][r] * acc[0][rb][1][r];
        float s1 = acc[0][rb][2][r] * acc[0][rb][2][r] + acc[0][rb][3][r] * acc[0][rb][3][r];
        s0 = qred16(s0); s1 = qred16(s1);
        float i0 = 1.0f / fmaxf(sqrtf(s0), 1e-12f);
        float i1 = 1.0f / fmaxf(sqrtf(s1), 1e-12f);
        acc[0][rb][0][r] *= i0; acc[0][rb][1][r] *= i0;
        acc[0][rb][2][r] *= i1; acc[0][rb][3][r] *= i1;
      }
    }
    // even lanes write full KQi 16B group {k0,k1,q0,q1}
    #pragma unroll
    for (int rb = 0; rb < 2; ++rb) {
      #pragma unroll
      for (int cb = 0; cb < 4; ++cb) {
        int rem = bn0 + cb * 16 + (lane & 15);
        int h = rem >> 5, d = rem & 31;
        #pragma unroll
        for (int r = 0; r < 4; ++r) {
          int m = bm0 + w * 32 + rb * 16 + (lane >> 4) * 4 + r;
          int bb = m >> 12, tt = m & 4095;
          size_t tok = ((size_t)(bb * NH + h) * T_ + tt);
          float kv = acc[0][rb][cb][r], qv = acc[1][rb][cb][r];
          float kn = dpp_xor1(kv), qn = dpp_xor1(qv);
          if ((lane & 1) == 0)
            *(float4*)&KQi[tok * 64 + (d >> 1) * 4] = (float4){kv, kn, qv, qn};
          gate[(size_t)m * SD + rem] = acc[2][rb][cb][r];
        }
      }
    }
  } else {
    // one full 16B AVB group {alpha, v, beta, 0} per lane
    #pragma unroll
    for (int rb = 0; rb < 2; ++rb) {
      #pragma unroll
      for (int cb = 0; cb < 4; ++cb) {
        int rem = bn0 + cb * 16 + (lane & 15);
        int h = rem >> 5, d = rem & 31;
        #pragma unroll
        for (int r = 0; r < 4; ++r) {
          int m = bm0 + w * 32 + rb * 16 + (lane >> 4) * 4 + r;
          int bb = m >> 12, tt = m & 4095;
          size_t tok = ((size_t)(bb * NH + h) * T_ + tt);
          float av = 1.0f / (1.0f + expf(-(acc[0][rb][cb][r] + b_alpha[rem])));
          float vv = acc[1][rb][cb][r];
          float bv = 1.0f / (1.0f + expf(-(acc[2][rb][cb][r] + b_beta[rem])));
          *(float4*)&AVBf[(tok * HD + d) * 4] = (float4){av, vv, bv, 0.0f};
        }
      }
    }
  }
}

// ---------------------------------------------------------------- sequential scan
// 512 blocks x 128 threads. block = (rg, bh): bh = blk&63, rg = blk>>6 (4 rows).
// WAVE0: lane = row il (lw>>4) x part p (lw&15), 2 cols/lane (one f2).
// 2-STEP LOOKAHEAD per pair (t=2j even): W0 = S.k_t, W1 = S.k_{t+1} (both from
// the pre-pair state -> their qred16s run in parallel); u_t = bt(vt - at W0);
// u_{t+1} = c1 - c2 u_t with c2 = bu au G_t, G_t = k_t . k_{t+1} (from wave1,
// stashed in the AVB pad word of even t). S_t, S_{t+1} by rank-1 pk-fma.
// Per pair: 4 ds_read_b128 + 2 ring ds_write_b32. lgkm ledger: prologue WKA(4),
// steady WKA(6) (retires 2 old writes + the pair's 4 reads), tail WKA(6)/WKA(2).
// WAVE1: stages chunks (KQ 8KB + AVB 2KB per buf) via global_load_lds;
// computes G per pair from GLOBAL KQ (L2-hot, same XCD: blk%8 == bh%8), quad
// DPP-reduce, ds_write into the staged AVB pads + lgkmcnt(0) BEFORE the
// publishing barrier; REDUCE unchanged from r10 (ring -> ctx).
// LDS: KQ dbuf 16KB @0, AVB dbuf 4KB @16384, ring 4x4KB @20480 = 36 KB.
#define CH 32
#define NCH (T_/CH)

#define DSR(dst, areg, imm) \
  asm volatile("ds_read_b128 %0, %1 offset:%c2" : "=v"(dst) : "v"(areg), "i"(imm))

#define SHUF2(V,A,B) __builtin_shufflevector(V, V, A, B)

#define BAR asm volatile("s_barrier" ::: "memory")

__global__ void __launch_bounds__(128, 1) scan_kernel(
    const float* __restrict__ KQi, const float4* __restrict__ AVB,
    const float* __restrict__ state_in,
    float* __restrict__ ctx, float* __restrict__ Sfin)
{
  __shared__ __align__(16) char Lds[36864];
  const int blk = blockIdx.x;
  const int bh = blk & 63, rg = blk >> 6;
  const int b = bh >> 3, h = bh & 7;
  const int tid = threadIdx.x;
  const int wid = tid >> 6;
  const int lw = tid & 63;

  const float*  KQg = KQi + (size_t)bh * (T_ * 64);
  const float4* Vg  = AVB + (size_t)bh * (T_ * HD) + rg * 4;

  const uint32_t lds0 = (uint32_t)(uintptr_t)(__attribute__((address_space(3))) char*)&Lds[0];

  if (wid == 1) {
    // ---------------- WAVE1: producer + G-computer + readout reducer ----------------
    const int il1 = lw >> 4, tq = lw & 15;
    const uint32_t a_pr = lds0 + 20480 + tq * 256 + il1 * 64;
    float* ctxb = ctx + (size_t)b * T_ * SD + h * HD + rg * 4 + il1;

    // G lanes: pair gpp (0..15), row gqt (0..3)
    const int gpp = lw >> 2, gqt = lw & 3;
    f4 gx0, gx1, gx2, gx3, gy0, gy1, gy2, gy3;
    const uint32_t a_gw = lds0 + 16384 + (2 * gpp) * 64 + gqt * 16 + 12;

    auto stageW = [&](int c2, int buf) {
      const float* kqg = KQg + (size_t)c2 * (CH * 64);
      #pragma unroll
      for (int it = 0; it < 8; ++it)
        gload16(kqg + (size_t)(lw + it * 64) * 4, Lds + buf * 8192 + it * 1024);
      const float4* vg = Vg + (size_t)c2 * (CH * HD);
      #pragma unroll
      for (int it = 0; it < 2; ++it) {
        int tc = it * 16 + (lw >> 2), r = lw & 3;
        gload16(vg + (size_t)tc * HD + r, Lds + 16384 + buf * 2048 + it * 1024);
      }
    };

    auto gfetch = [&](int c2) {
      const float* gp = KQg + ((size_t)c2 * CH + 2 * gpp) * 64 + gqt * 16;
      gx0 = *(const f4*)(gp);      gx1 = *(const f4*)(gp + 4);
      gx2 = *(const f4*)(gp + 8);  gx3 = *(const f4*)(gp + 12);
      gy0 = *(const f4*)(gp + 64); gy1 = *(const f4*)(gp + 68);
      gy2 = *(const f4*)(gp + 72); gy3 = *(const f4*)(gp + 76);
    };

    auto gwrite = [&](int buf) {
      f2 g2 = SHUF2(gx0, 0, 1) * SHUF2(gy0, 0, 1);
      g2 = __builtin_elementwise_fma(SHUF2(gx1, 0, 1), SHUF2(gy1, 0, 1), g2);
      g2 = __builtin_elementwise_fma(SHUF2(gx2, 0, 1), SHUF2(gy2, 0, 1), g2);
      g2 = __builtin_elementwise_fma(SHUF2(gx3, 0, 1), SHUF2(gy3, 0, 1), g2);
      float G = g2.x + g2.y;
      G += __int_as_float(__builtin_amdgcn_mov_dpp(__float_as_int(G), 0xB1, 0xF, 0xF, true));
      G += __int_as_float(__builtin_amdgcn_mov_dpp(__float_as_int(G), 0x4E, 0xF, 0xF, true));
      uint32_t aw = a_gw + buf * 2048;
      asm volatile("ds_write_b32 %0, %1" :: "v"(aw), "v"(G));
      asm volatile("s_waitcnt lgkmcnt(0)" ::: "memory");   // writes land before BAR
    };

#define REDUCE(PB, T0) do { \
      f4 r0_, r1_, r2_, r3_; \
      DSR(r0_, a_pr, (PB)*4096 + 0);  DSR(r1_, a_pr, (PB)*4096 + 16); \
      DSR(r2_, a_pr, (PB)*4096 + 32); DSR(r3_, a_pr, (PB)*4096 + 48); \
      asm volatile("s_waitcnt lgkmcnt(0)" : "+v"(r0_), "+v"(r1_), "+v"(r2_), "+v"(r3_)); \
      f4 s_ = (r0_ + r1_) + (r2_ + r3_); \
      float v_ = (s_.x + s_.y) + (s_.z + s_.w); \
      ctxb[(size_t)((T0) + tq) * SD] = v_; \
    } while (0)

    gfetch(0);
    stageW(0, 0);
    asm volatile("s_waitcnt vmcnt(0)" ::: "memory");
    gwrite(0);
    BAR;   // prologue: chunk 0 staged + G in pads
    #pragma unroll 1
    for (int cp = 0; cp < NCH / 2; ++cp) {
      if (cp > 0) REDUCE(2, 64 * cp - 32);
      gfetch(2 * cp + 1);
      stageW(2 * cp + 1, 1);
      BAR;
      if (cp > 0) REDUCE(3, 64 * cp - 16);
      asm volatile("s_waitcnt vmcnt(0)" ::: "memory");
      gwrite(1);
      BAR;                                   // publishes chunk 2cp+1
      REDUCE(0, 64 * cp);
      if (cp < NCH / 2 - 1) { gfetch(2 * cp + 2); stageW(2 * cp + 2, 0); }
      BAR;
      REDUCE(1, 64 * cp + 16);
      asm volatile("s_waitcnt vmcnt(0)" ::: "memory");
      if (cp < NCH / 2 - 1) gwrite(0);
      BAR;                                   // publishes chunk 2cp+2
    }
    BAR;  // final sync (wave0 drained its last partial writes)
    REDUCE(2, T_ - 32);
    REDUCE(3, T_ - 16);
#undef REDUCE
    return;
  }

  // ---------------- WAVE0: the sequential recurrence (2-step pairs) ----------------
  const int il = lw >> 4;    // local row
  const int p  = lw & 15;    // column part (cols 2p, 2p+1)

  f2 S2;
  {
    const float* sp = state_in + (size_t)bh * 1024 + (rg * 4 + il) * 32 + p * 2;
    S2 = (f2){sp[0], sp[1]};
  }

  const uint32_t a_kq = lds0 + p * 16;
  const uint32_t a_v  = lds0 + 16384 + il * 16;
  const uint32_t a_pw = lds0 + 20480 + lw * 4;

  f4 kqA, vvA, kqB, vvB, kqC, vvC, kqD, vvD;

#define R2(X, Y, BUF, J) do { \
    DSR(kq##X, a_kq, (BUF)*8192 + (2*(J))*256); \
    DSR(vv##X, a_v,  (BUF)*2048 + (2*(J))*64); \
    DSR(kq##Y, a_kq, (BUF)*8192 + (2*(J)+1)*256); \
    DSR(vv##Y, a_v,  (BUF)*2048 + (2*(J)+1)*64); \
  } while (0)

#define WKA2(N, X, Y) \
    asm volatile("s_waitcnt lgkmcnt(" #N ")" \
                 : "+v"(kq##X), "+v"(vv##X), "+v"(kq##Y), "+v"(vv##Y))

// pair compute: X holds even step T0 (with G in vv.w), Y holds T0+1
#define C2(X, Y, T0, PB) do { \
    f2 k0_ = SHUF2(kq##X, 0, 1), q0_ = SHUF2(kq##X, 2, 3); \
    f2 k1_ = SHUF2(kq##Y, 0, 1), q1_ = SHUF2(kq##Y, 2, 3); \
    f4 VA_ = vv##X, VB_ = vv##Y; \
    f2 dA_ = k0_ * S2, dB_ = k1_ * S2; \
    float W0_ = qred16(dA_.x + dA_.y); \
    float W1_ = qred16(dB_.x + dB_.y); \
    float u0_ = fmaf(-(VA_.z * VA_.x), W0_, VA_.z * VA_.y); \
    float bua_ = VB_.z * VB_.x; \
    float c2_ = bua_ * VA_.w; \
    float c1_ = fmaf(-(bua_ * VA_.x), W1_, VB_.z * VB_.y); \
    float u1_ = fmaf(-c2_, u0_, c1_); \
    f2 St_ = __builtin_elementwise_fma((f2){u0_, u0_}, k0_, (f2){VA_.x, VA_.x} * S2); \
    f2 Su_ = __builtin_elementwise_fma((f2){u1_, u1_}, k1_, (f2){VB_.x, VB_.x} * St_); \
    f2 o0_ = q0_ * St_; \
    f2 o1_ = q1_ * Su_; \
    float p0_ = o0_.x + o0_.y; \
    float p1_ = o1_.x + o1_.y; \
    S2 = Su_; \
    asm volatile("ds_write_b32 %0, %1 offset:%c2" :: "v"(a_pw), "v"(p0_), "i"((PB)*4096 + ((T0)&15)*256)); \
    asm volatile("ds_write_b32 %0, %1 offset:%c2" :: "v"(a_pw), "v"(p1_), "i"((PB)*4096 + (((T0)+1)&15)*256)); \
  } while (0)

#define CHUNK(BUF, PBa, PBb) do { \
    R2(A,B,BUF,0); R2(C,D,BUF,1); \
    WKA2(4,A,B); C2(A,B, 0,PBa); R2(A,B,BUF,2); \
    WKA2(6,C,D); C2(C,D, 2,PBa); R2(C,D,BUF,3); \
    WKA2(6,A,B); C2(A,B, 4,PBa); R2(A,B,BUF,4); \
    WKA2(6,C,D); C2(C,D, 6,PBa); R2(C,D,BUF,5); \
    WKA2(6,A,B); C2(A,B, 8,PBa); R2(A,B,BUF,6); \
    WKA2(6,C,D); C2(C,D,10,PBa); R2(C,D,BUF,7); \
    WKA2(6,A,B); C2(A,B,12,PBa); R2(A,B,BUF,8); \
    WKA2(6,C,D); C2(C,D,14,PBa); R2(C,D,BUF,9); \
    BAR; \
    WKA2(6,A,B); C2(A,B,16,PBb); R2(A,B,BUF,10); \
    WKA2(6,C,D); C2(C,D,18,PBb); R2(C,D,BUF,11); \
    WKA2(6,A,B); C2(A,B,20,PBb); R2(A,B,BUF,12); \
    WKA2(6,C,D); C2(C,D,22,PBb); R2(C,D,BUF,13); \
    WKA2(6,A,B); C2(A,B,24,PBb); R2(A,B,BUF,14); \
    WKA2(6,C,D); C2(C,D,26,PBb); R2(C,D,BUF,15); \
    WKA2(6,A,B); C2(A,B,28,PBb); \
    WKA2(2,C,D); C2(C,D,30,PBb); \
    BAR; \
  } while (0)

  BAR;   // prologue: wait for wave1's stage(0)+G(0)
  #pragma unroll 1
  for (int cp = 0; cp < NCH / 2; ++cp) {
    CHUNK(0, 0, 1);
    CHUNK(1, 2, 3);
  }
  asm volatile("s_waitcnt lgkmcnt(0)" ::: "memory");
  BAR;   // final: partial writes of last group retired/visible

  {
    float* sp = Sfin + (size_t)bh * 1024 + (rg * 4 + il) * 32 + p * 2;
    sp[0] = S2.x; sp[1] = S2.y;
  }
#undef C2
#undef R2
#undef WKA2
#undef CHUNK
}

// ---------------------------------------------------------------- rmsnorm * silu(gate) -> bf16
__global__ void __launch_bounds__(256) rms_silu(
    const float* __restrict__ ctx, const float* __restrict__ gate,
    const float* __restrict__ norm_w, unsigned short* __restrict__ ctx2)
{
  size_t row = (size_t)blockIdx.x * 4 + (threadIdx.x >> 6);
  int lane = threadIdx.x & 63;
  const float4 x = *(const float4*)&ctx[row * SD + lane * 4];
  float s = x.x * x.x + x.y * x.y + x.z * x.z + x.w * x.w;
  #pragma unroll
  for (int m = 32; m >= 1; m >>= 1) s += __shfl_xor(s, m, 64);
  float rs = 1.0f / sqrtf(s * (1.0f / 256.0f) + 1e-6f);
  const float4 g = *(const float4*)&gate[row * SD + lane * 4];
  const float4 w = *(const float4*)&norm_w[lane * 4];
  ushort4 o;
  o.x = f2bf(x.x * rs * w.x * (g.x / (1.0f + expf(-g.x))));
  o.y = f2bf(x.y * rs * w.y * (g.y / (1.0f + expf(-g.y))));
  o.z = f2bf(x.z * rs * w.z * (g.z / (1.0f + expf(-g.z))));
  o.w = f2bf(x.w * rs * w.w * (g.w / (1.0f + expf(-g.w))));
  *(ushort4*)&ctx2[row * SD + lane * 4] = o;
}

// ---------------------------------------------------------------- output GEMM
__global__ void __launch_bounds__(256) out_gemm(
    const unsigned short* __restrict__ ctx2, const unsigned short* __restrict__ Wob,
    float* __restrict__ out)
{
  __shared__ unsigned short Asm[PM*PK];
  __shared__ unsigned short Bsm[PN*PK];
  const int t = threadIdx.x;
  const int w = t >> 6, lane = t & 63;
  const int bm0 = blockIdx.x * PM;
  const int bn0 = blockIdx.y * PN;

  f32x4 acc[2][4];
  #pragma unroll
  for (int i = 0; i < 2; ++i)
    #pragma unroll
    for (int j = 0; j < 4; ++j) acc[i][j] = (f32x4){0.f, 0.f, 0.f, 0.f};

  for (int k0 = 0; k0 < SD; k0 += PK) {
    #pragma unroll
    for (int it = 0; it < 4; ++it) {
      int unit = t + it * 256;
      int row = unit >> 3, seg = unit & 7;
      int dseg = seg ^ (row & 7);
      const unsigned short* g = ctx2 + (size_t)(bm0 + row) * SD + k0 + dseg * 8;
      gload16(g, (char*)Asm + (w * 1024 + it * 4096));
    }
    #pragma unroll
    for (int it = 0; it < 2; ++it) {
      int unit = t + it * 256;
      int n = unit >> 3, seg = unit & 7;
      int dseg = seg ^ (n & 7);
      const unsigned short* g = Wob + (size_t)(bn0 + n) * SD + k0 + dseg * 8;
      gload16(g, (char*)Bsm + (w * 1024 + it * 4096));
    }
    __syncthreads();
    #pragma unroll
    for (int ks = 0; ks < 2; ++ks) {
      short8 af[2], bfr[4];
      int u = ks * 4 + (lane >> 4);
      int slot = u ^ (lane & 7);
      #pragma unroll
      for (int rb = 0; rb < 2; ++rb) {
        int row = w * 32 + rb * 16 + (lane & 15);
        af[rb] = *(const short8*)((const char*)Asm + row * 128 + slot * 16);
      }
      #pragma unroll
      for (int cb = 0; cb < 4; ++cb) {
        int nn = cb * 16 + (lane & 15);
        bfr[cb] = *(const short8*)((const char*)Bsm + nn * 128 + slot * 16);
      }
      #pragma unroll
      for (int rb = 0; rb < 2; ++rb)
        #pragma unroll
        for (int cb = 0; cb < 4; ++cb)
          acc[rb][cb] = __builtin_amdgcn_mfma_f32_16x16x32_bf16(af[rb], bfr[cb], acc[rb][cb], 0, 0, 0);
    }
    __syncthreads();
  }
  #pragma unroll
  for (int rb = 0; rb < 2; ++rb)
    #pragma unroll
    for (int cb = 0; cb < 4; ++cb) {
      int n = bn0 + cb * 16 + (lane & 15);
      #pragma unroll
      for (int r = 0; r < 4; ++r) {
        int m = bm0 + w * 32 + rb * 16 + (lane >> 4) * 4 + r;
        out[(size_t)m * 512 + n] = acc[rb][cb][r];
      }
    }
}

// ---------------------------------------------------------------- launcher
// ws layout (bytes), total 253,493,248:
//   hb   bf16 [32768][512]            @ 0
//   Wc   bf16 [1536][512]             @ 33,554,432
//   Wob  bf16 [512][256]              @ 35,127,296
//   KQi  f32  [64][4096][64]          @ 35,389,440   (16 groups x [k2, q2])
//   AVB  f32x4 [64][4096][32]         @ 102,498,304  (a, v, beta, pad/G)
//   ctx2 bf16 [32768][256]            @ 236,716,032
// d_out reuse: ctx f32 [32768][256] @ 0; gate f32 [32768][256] @ +8388608 floats
// (both overwritten later by out_gemm); Sfin @ +16777216 floats.
extern "C" void kernel_launch(void* const* d_in, const int* in_sizes, int n_in,
                              void* d_out, int out_size, void* d_ws, size_t ws_size,
                              hipStream_t stream) {
  (void)in_sizes; (void)n_in; (void)out_size; (void)ws_size;
  const float* hidden  = (const float*)d_in[0];
  const float* state   = (const float*)d_in[1];
  const float* W_k     = (const float*)d_in[2];
  const float* W_v     = (const float*)d_in[3];
  const float* W_q     = (const float*)d_in[4];
  const float* W_beta  = (const float*)d_in[5];
  const float* b_beta  = (const float*)d_in[6];
  const float* W_alpha = (const float*)d_in[7];
  const float* b_alpha = (const float*)d_in[8];
  const float* W_out   = (const float*)d_in[9];
  const float* gate_W  = (const float*)d_in[10];
  const float* norm_w  = (const float*)d_in[11];
  float* out = (float*)d_out;

  char* ws = (char*)d_ws;
  unsigned short* hb  = (unsigned short*)(ws);
  unsigned short* Wc  = (unsigned short*)(ws + 33554432);
  unsigned short* Wob = (unsigned short*)(ws + 35127296);
  float* KQi  = (float*)(ws + 35389440);
  float* AVBf = (float*)(ws + 102498304);
  unsigned short* ctx2 = (unsigned short*)(ws + 236716032);
  float* ctx  = out;                 // fp32 scratch, overwritten by out_gemm
  float* gate = out + 8388608;       // fp32 scratch, overwritten by out_gemm
  float* Sfin = out + 16777216;      // final state output

  cvt_f32_bf16<<<2048, 256, 0, stream>>>(hidden, hb, M_TOK * HID / 4);
  cvt_weights<<<dim3(128, 7), 256, 0, stream>>>(W_k, W_v, W_q, W_beta, W_alpha, gate_W, W_out, Wc, Wob);

  proj_gemm<<<dim3(256, 8), 256, 0, stream>>>(hb, Wc, b_beta, b_alpha, KQi, AVBf, gate);
  scan_kernel<<<512, 128, 0, stream>>>(KQi, (const float4*)AVBf, state, ctx, Sfin);
  rms_silu<<<8192, 256, 0, stream>>>(ctx, gate, norm_w, ctx2);
  out_gemm<<<dim3(256, 8), 256, 0, stream>>>(ctx2, Wob, out);
}

// Round 14
// 401.494 us; speedup vs baseline: 1.1765x; 1.0770x over previous
//
#include <hip/hip_runtime.h>
#include <stdint.h>

// Problem constants
#define B_    8
#define T_    4096
#define HID   512
#define SD    256
#define NH    8
#define HD    32
#define M_TOK (B_*T_)          // 32768 tokens

typedef __attribute__((ext_vector_type(8))) short short8;   // 8 bf16 (4 VGPRs) — MFMA A/B frag
typedef __attribute__((ext_vector_type(4))) float f32x4;    // MFMA C/D frag
typedef __attribute__((ext_vector_type(4))) float f4;       // reg-tuple 4xf32 (asm-safe)
typedef __attribute__((ext_vector_type(2))) float f2;       // packed fp32 (v_pk_*_f32)

__device__ __forceinline__ unsigned short f2bf(float f) {
  uint32_t u = __float_as_uint(f);
  uint32_t r = (u + 0x7fffu + ((u >> 16) & 1u)) >> 16;
  return (unsigned short)r;
}

__device__ __forceinline__ void gload16(const void* g, void* l) {
  // async global->LDS, 16B per lane; LDS dest = wave-uniform base + lane*16
  __builtin_amdgcn_global_load_lds((const __attribute__((address_space(1))) void*)g,
                                   (__attribute__((address_space(3))) void*)l,
                                   16, 0, 0);
}

// butterfly sum across 16 consecutive lanes — pure VALU (DPP), no DS pipe.
__device__ __forceinline__ float qred16(float x) {
  x += __int_as_float(__builtin_amdgcn_mov_dpp(__float_as_int(x), 0xB1,  0xF, 0xF, true));
  x += __int_as_float(__builtin_amdgcn_mov_dpp(__float_as_int(x), 0x4E,  0xF, 0xF, true));
  x += __int_as_float(__builtin_amdgcn_mov_dpp(__float_as_int(x), 0x141, 0xF, 0xF, true));
  x += __int_as_float(__builtin_amdgcn_mov_dpp(__float_as_int(x), 0x128, 0xF, 0xF, true));
  return x;
}

// value of lane^1 (quad_perm [1,0,3,2]) — pure VALU
__device__ __forceinline__ float dpp_xor1(float x) {
  return __int_as_float(__builtin_amdgcn_mov_dpp(__float_as_int(x), 0xB1, 0xF, 0xF, true));
}

// ---------------------------------------------------------------- converts
__global__ void cvt_f32_bf16(const float* __restrict__ in, unsigned short* __restrict__ out, int n4) {
  int i = blockIdx.x * blockDim.x + threadIdx.x;
  int stride = gridDim.x * blockDim.x;
  for (; i < n4; i += stride) {
    float4 v = reinterpret_cast<const float4*>(in)[i];
    ushort4 o;
    o.x = f2bf(v.x); o.y = f2bf(v.y); o.z = f2bf(v.z); o.w = f2bf(v.w);
    reinterpret_cast<ushort4*>(out)[i] = o;
  }
}

// all 7 weight matrices in one launch: grid (128, 7), 32768 float4 per slice
__global__ void __launch_bounds__(256) cvt_weights(
    const float* __restrict__ W_k, const float* __restrict__ W_v,
    const float* __restrict__ W_q, const float* __restrict__ W_beta,
    const float* __restrict__ W_alpha, const float* __restrict__ gate_W,
    const float* __restrict__ W_out,
    unsigned short* __restrict__ Wc, unsigned short* __restrict__ Wob)
{
  int slice = blockIdx.y;
  const float* src = (slice == 0) ? W_k : (slice == 1) ? W_v : (slice == 2) ? W_q :
                     (slice == 3) ? W_beta : (slice == 4) ? W_alpha : (slice == 5) ? gate_W : W_out;
  unsigned short* dst = (slice == 6) ? Wob : (Wc + slice * 131072);
  int i = blockIdx.x * 256 + threadIdx.x;   // 0..32767 float4 units
  float4 v = reinterpret_cast<const float4*>(src)[i];
  ushort4 o;
  o.x = f2bf(v.x); o.y = f2bf(v.y); o.z = f2bf(v.z); o.w = f2bf(v.w);
  reinterpret_cast<ushort4*>(dst)[i] = o;
}

// ---------------------------------------------------------------- projection GEMM (fused 3-way)
// grid (256, 8): role 0-3: col-tile of {k, q, gate}; role 4-7: {alpha, v, beta}.
// KQi layout: [tok][16 groups g][k_{2g} k_{2g+1} q_{2g} q_{2g+1}] (16B/group).
// Epilogue writes FULL 16B groups per store (KQi via lane^1 DPP pair-exchange,
// even lanes store float4 {k0,k1,q0,q1}; AVB one float4 {a,v,b,0} per lane).
// k-normalization fused in-register (16-lane qred16 per token-half).
#define PM 128
#define PN 64
#define PK 64

__global__ void __launch_bounds__(256) proj_gemm(
    const unsigned short* __restrict__ hb, const unsigned short* __restrict__ Wc,
    const float* __restrict__ b_beta, const float* __restrict__ b_alpha,
    float* __restrict__ KQi, float* __restrict__ AVBf, float* __restrict__ gate)
{
  __shared__ unsigned short Asm[PM*PK];      // 16 KB
  __shared__ unsigned short Bsm[3][PN*PK];   // 24 KB
  const int t = threadIdx.x;
  const int w = t >> 6, lane = t & 63;
  const int bm0 = blockIdx.x * PM;
  const int role = blockIdx.y;
  const int grp = role >> 2;       // 0 = {k,q,gate}, 1 = {alpha,v,beta}
  const int bn0 = (role & 3) * 64; // column offset within each projection (0..255)
  const int pr0 = grp ? 4 : 0, pr1 = grp ? 1 : 2, pr2 = grp ? 3 : 5;

  f32x4 acc[3][2][4];
  #pragma unroll
  for (int pp = 0; pp < 3; ++pp)
    #pragma unroll
    for (int i = 0; i < 2; ++i)
      #pragma unroll
      for (int j = 0; j < 4; ++j) acc[pp][i][j] = (f32x4){0.f, 0.f, 0.f, 0.f};

  for (int k0 = 0; k0 < HID; k0 += PK) {
    #pragma unroll
    for (int it = 0; it < 4; ++it) {
      int unit = t + it * 256;
      int row = unit >> 3, seg = unit & 7;
      int dseg = seg ^ (row & 7);
      const unsigned short* g = hb + (size_t)(bm0 + row) * HID + k0 + dseg * 8;
      gload16(g, (char*)Asm + (w * 1024 + it * 4096));
    }
    #pragma unroll
    for (int pp = 0; pp < 3; ++pp) {
      const int pr = (pp == 0) ? pr0 : (pp == 1) ? pr1 : pr2;
      #pragma unroll
      for (int it = 0; it < 2; ++it) {
        int unit = t + it * 256;
        int n = unit >> 3, seg = unit & 7;
        int dseg = seg ^ (n & 7);
        const unsigned short* g = Wc + (size_t)(pr * 256 + bn0 + n) * HID + k0 + dseg * 8;
        gload16(g, (char*)Bsm[pp] + (w * 1024 + it * 4096));
      }
    }
    __syncthreads();
    #pragma unroll
    for (int ks = 0; ks < 2; ++ks) {
      short8 af[2];
      int u = ks * 4 + (lane >> 4);
      int slot = u ^ (lane & 7);
      #pragma unroll
      for (int rb = 0; rb < 2; ++rb) {
        int row = w * 32 + rb * 16 + (lane & 15);
        af[rb] = *(const short8*)((const char*)Asm + row * 128 + slot * 16);
      }
      #pragma unroll
      for (int pp = 0; pp < 3; ++pp) {
        short8 bfr[4];
        #pragma unroll
        for (int cb = 0; cb < 4; ++cb) {
          int nn = cb * 16 + (lane & 15);
          bfr[cb] = *(const short8*)((const char*)Bsm[pp] + nn * 128 + slot * 16);
        }
        #pragma unroll
        for (int rb = 0; rb < 2; ++rb)
          #pragma unroll
          for (int cb = 0; cb < 4; ++cb)
            acc[pp][rb][cb] = __builtin_amdgcn_mfma_f32_16x16x32_bf16(af[rb], bfr[cb], acc[pp][rb][cb], 0, 0, 0);
      }
    }
    __syncthreads();
  }

  if (grp == 0) {
    // fused k-normalization (16-lane DPP row covers all 32 d of one (m,h))
    #pragma unroll
    for (int rb = 0; rb < 2; ++rb) {
      #pragma unroll
      for (int r = 0; r < 4; ++r) {
        float s0 = acc[0][rb][0][r] * acc[0][rb][0][r] + acc[0][rb][1][r] * acc[0][rb][1][r];
        float s1 = acc[0][rb][2][r] * acc[0][rb][2][r] + acc[0][rb][3][r] * acc[0][rb][3][r];
        s0 = qred16(s0); s1 = qred16(s1);
        float i0 = 1.0f / fmaxf(sqrtf(s0), 1e-12f);
        float i1 = 1.0f / fmaxf(sqrtf(s1), 1e-12f);
        acc[0][rb][0][r] *= i0; acc[0][rb][1][r] *= i0;
        acc[0][rb][2][r] *= i1; acc[0][rb][3][r] *= i1;
      }
    }
    // even lanes write full KQi 16B group {k0,k1,q0,q1}
    #pragma unroll
    for (int rb = 0; rb < 2; ++rb) {
      #pragma unroll
      for (int cb = 0; cb < 4; ++cb) {
        int rem = bn0 + cb * 16 + (lane & 15);
        int h = rem >> 5, d = rem & 31;
        #pragma unroll
        for (int r = 0; r < 4; ++r) {
          int m = bm0 + w * 32 + rb * 16 + (lane >> 4) * 4 + r;
          int bb = m >> 12, tt = m & 4095;
          size_t tok = ((size_t)(bb * NH + h) * T_ + tt);
          float kv = acc[0][rb][cb][r], qv = acc[1][rb][cb][r];
          float kn = dpp_xor1(kv), qn = dpp_xor1(qv);
          if ((lane & 1) == 0)
            *(float4*)&KQi[tok * 64 + (d >> 1) * 4] = (float4){kv, kn, qv, qn};
          gate[(size_t)m * SD + rem] = acc[2][rb][cb][r];
        }
      }
    }
  } else {
    // one full 16B AVB group {alpha, v, beta, 0} per lane
    #pragma unroll
    for (int rb = 0; rb < 2; ++rb) {
      #pragma unroll
      for (int cb = 0; cb < 4; ++cb) {
        int rem = bn0 + cb * 16 + (lane & 15);
        int h = rem >> 5, d = rem & 31;
        #pragma unroll
        for (int r = 0; r < 4; ++r) {
          int m = bm0 + w * 32 + rb * 16 + (lane >> 4) * 4 + r;
          int bb = m >> 12, tt = m & 4095;
          size_t tok = ((size_t)(bb * NH + h) * T_ + tt);
          float av = 1.0f / (1.0f + expf(-(acc[0][rb][cb][r] + b_alpha[rem])));
          float vv = acc[1][rb][cb][r];
          float bv = 1.0f / (1.0f + expf(-(acc[2][rb][cb][r] + b_beta[rem])));
          *(float4*)&AVBf[(tok * HD + d) * 4] = (float4){av, vv, bv, 0.0f};
        }
      }
    }
  }
}

// ---------------------------------------------------------------- sequential scan
// 512 blocks x 128 threads. block = (rg, bh): bh = blk&63, rg = blk>>6 (8 groups
// of 4 rows). WAVE0: lane = row il (lw>>4) x part p (lw&15), 2 cols/lane (one f2).
// 2-step lookahead pairs (r13 algebra): W0, W1 from the pre-pair state (parallel
// qred16s); u1 = c1 - c2*u0 with c2 = b1 a1 G, G = k_t.k_{t+1} in AVB pad (wave1).
// NEW vs r13: NO partial ring. Readout o0/o1 reduced in-wave via qred16 (off the
// recurrence chain, pure-VALU overlap), lane-selected (p == step&15), ONE global
// dword store per lane per 16 steps. Per pair DS = 4 ds_read_b128 only. lgkm
// ledger: steady WKA(4) (two 4-read pair-sets in flight), tail WKA(0). ONE
// s_barrier per 32-step chunk. WAVE1: stage chunk c+1 + gfetch/gwrite(G) only;
// vmcnt(0) then gwrite then lgkm(0)+BAR (G write must land after gload_lds data).
// LDS: KQ dbuf 16KB @0, AVB dbuf 4KB @16384 = 20.5 KB. 129 barriers each wave.
#define CH 32
#define NCH (T_/CH)

#define DSR(dst, areg, imm) \
  asm volatile("ds_read_b128 %0, %1 offset:%c2" : "=v"(dst) : "v"(areg), "i"(imm))

#define SHUF2(V,A,B) __builtin_shufflevector(V, V, A, B)

#define BAR asm volatile("s_barrier" ::: "memory")

__global__ void __launch_bounds__(128, 1) scan_kernel(
    const float* __restrict__ KQi, const float4* __restrict__ AVB,
    const float* __restrict__ state_in,
    float* __restrict__ ctx, float* __restrict__ Sfin)
{
  __shared__ __align__(16) char Lds[20480];
  const int blk = blockIdx.x;
  const int bh = blk & 63, rg = blk >> 6;
  const int b = bh >> 3, h = bh & 7;
  const int tid = threadIdx.x;
  const int wid = tid >> 6;
  const int lw = tid & 63;

  const float*  KQg = KQi + (size_t)bh * (T_ * 64);
  const float4* Vg  = AVB + (size_t)bh * (T_ * HD) + rg * 4;

  const uint32_t lds0 = (uint32_t)(uintptr_t)(__attribute__((address_space(3))) char*)&Lds[0];

  if (wid == 1) {
    // ---------------- WAVE1: producer (staging + G) ----------------
    const int gpp = lw >> 2, gqt = lw & 3;   // pair 0..15, row 0..3
    f4 gx0, gx1, gx2, gx3, gy0, gy1, gy2, gy3;
    const uint32_t a_gw = lds0 + 16384 + (2 * gpp) * 64 + gqt * 16 + 12;

    auto stageW = [&](int c2, int buf) {
      const float* kqg = KQg + (size_t)c2 * (CH * 64);
      #pragma unroll
      for (int it = 0; it < 8; ++it)
        gload16(kqg + (size_t)(lw + it * 64) * 4, Lds + buf * 8192 + it * 1024);
      const float4* vg = Vg + (size_t)c2 * (CH * HD);
      #pragma unroll
      for (int it = 0; it < 2; ++it) {
        int tc = it * 16 + (lw >> 2), r = lw & 3;
        gload16(vg + (size_t)tc * HD + r, Lds + 16384 + buf * 2048 + it * 1024);
      }
    };

    auto gfetch = [&](int c2) {
      const float* gp = KQg + ((size_t)c2 * CH + 2 * gpp) * 64 + gqt * 16;
      gx0 = *(const f4*)(gp);      gx1 = *(const f4*)(gp + 4);
      gx2 = *(const f4*)(gp + 8);  gx3 = *(const f4*)(gp + 12);
      gy0 = *(const f4*)(gp + 64); gy1 = *(const f4*)(gp + 68);
      gy2 = *(const f4*)(gp + 72); gy3 = *(const f4*)(gp + 76);
    };

    auto gwrite = [&](int buf) {
      f2 g2 = SHUF2(gx0, 0, 1) * SHUF2(gy0, 0, 1);
      g2 = __builtin_elementwise_fma(SHUF2(gx1, 0, 1), SHUF2(gy1, 0, 1), g2);
      g2 = __builtin_elementwise_fma(SHUF2(gx2, 0, 1), SHUF2(gy2, 0, 1), g2);
      g2 = __builtin_elementwise_fma(SHUF2(gx3, 0, 1), SHUF2(gy3, 0, 1), g2);
      float G = g2.x + g2.y;
      G += __int_as_float(__builtin_amdgcn_mov_dpp(__float_as_int(G), 0xB1, 0xF, 0xF, true));
      G += __int_as_float(__builtin_amdgcn_mov_dpp(__float_as_int(G), 0x4E, 0xF, 0xF, true));
      uint32_t aw = a_gw + buf * 2048;
      asm volatile("ds_write_b32 %0, %1" :: "v"(aw), "v"(G));
      asm volatile("s_waitcnt lgkmcnt(0)" ::: "memory");   // G lands before BAR
    };

    gfetch(0);
    stageW(0, 0);
    asm volatile("s_waitcnt vmcnt(0)" ::: "memory");
    gwrite(0);
    BAR;   // prologue: chunk 0 staged + G in pads
    #pragma unroll 1
    for (int c = 0; c < NCH; ++c) {
      if (c + 1 < NCH) {
        gfetch(c + 1);
        stageW(c + 1, (c + 1) & 1);
        asm volatile("s_waitcnt vmcnt(0)" ::: "memory");
        gwrite((c + 1) & 1);
      }
      BAR;
    }
    return;
  }

  // ---------------- WAVE0: the sequential recurrence (2-step pairs) ----------------
  const int il = lw >> 4;    // local row
  const int p  = lw & 15;    // column part (cols 2p, 2p+1)

  f2 S2;
  {
    const float* sp = state_in + (size_t)bh * 1024 + (rg * 4 + il) * 32 + p * 2;
    S2 = (f2){sp[0], sp[1]};
  }

  const uint32_t a_kq = lds0 + p * 16;
  const uint32_t a_v  = lds0 + 16384 + il * 16;

  float osel = 0.0f;
  float* ctxp = ctx + (size_t)b * T_ * SD + (size_t)p * SD + h * HD + rg * 4 + il;

  f4 kqA, vvA, kqB, vvB, kqC, vvC, kqD, vvD;

#define R2(X, Y, BUF, J) do { \
    DSR(kq##X, a_kq, (BUF)*8192 + (2*(J))*256); \
    DSR(vv##X, a_v,  (BUF)*2048 + (2*(J))*64); \
    DSR(kq##Y, a_kq, (BUF)*8192 + (2*(J)+1)*256); \
    DSR(vv##Y, a_v,  (BUF)*2048 + (2*(J)+1)*64); \
  } while (0)

#define WKA2(N, X, Y) \
    asm volatile("s_waitcnt lgkmcnt(" #N ")" \
                 : "+v"(kq##X), "+v"(vv##X), "+v"(kq##Y), "+v"(vv##Y))

// pair compute: X holds even step T0 (with G in vv.w), Y holds T0+1.
// Readout qred16s are OFF the recurrence chain (ILP overlap with next pair).
#define C2(X, Y, T0) do { \
    f2 k0_ = SHUF2(kq##X, 0, 1), q0_ = SHUF2(kq##X, 2, 3); \
    f2 k1_ = SHUF2(kq##Y, 0, 1), q1_ = SHUF2(kq##Y, 2, 3); \
    f4 VA_ = vv##X, VB_ = vv##Y; \
    f2 dA_ = k0_ * S2, dB_ = k1_ * S2; \
    float W0_ = qred16(dA_.x + dA_.y); \
    float W1_ = qred16(dB_.x + dB_.y); \
    float u0_ = fmaf(-(VA_.z * VA_.x), W0_, VA_.z * VA_.y); \
    float bua_ = VB_.z * VB_.x; \
    float c2_ = bua_ * VA_.w; \
    float c1_ = fmaf(-(bua_ * VA_.x), W1_, VB_.z * VB_.y); \
    float u1_ = fmaf(-c2_, u0_, c1_); \
    f2 St_ = __builtin_elementwise_fma((f2){u0_, u0_}, k0_, (f2){VA_.x, VA_.x} * S2); \
    f2 Su_ = __builtin_elementwise_fma((f2){u1_, u1_}, k1_, (f2){VB_.x, VB_.x} * St_); \
    f2 o0_ = q0_ * St_; \
    f2 o1_ = q1_ * Su_; \
    S2 = Su_; \
    float od0_ = qred16(o0_.x + o0_.y); \
    float od1_ = qred16(o1_.x + o1_.y); \
    osel = (p == ((T0) & 15))       ? od0_ : osel; \
    osel = (p == (((T0) + 1) & 15)) ? od1_ : osel; \
    if ((((T0) + 1) & 15) == 15) { *ctxp = osel; ctxp += 16 * SD; } \
  } while (0)

#define CHUNK(BUF) do { \
    R2(A,B,BUF,0); R2(C,D,BUF,1); \
    WKA2(4,A,B); C2(A,B, 0); R2(A,B,BUF,2); \
    WKA2(4,C,D); C2(C,D, 2); R2(C,D,BUF,3); \
    WKA2(4,A,B); C2(A,B, 4); R2(A,B,BUF,4); \
    WKA2(4,C,D); C2(C,D, 6); R2(C,D,BUF,5); \
    WKA2(4,A,B); C2(A,B, 8); R2(A,B,BUF,6); \
    WKA2(4,C,D); C2(C,D,10); R2(C,D,BUF,7); \
    WKA2(4,A,B); C2(A,B,12); R2(A,B,BUF,8); \
    WKA2(4,C,D); C2(C,D,14); R2(C,D,BUF,9); \
    WKA2(4,A,B); C2(A,B,16); R2(A,B,BUF,10); \
    WKA2(4,C,D); C2(C,D,18); R2(C,D,BUF,11); \
    WKA2(4,A,B); C2(A,B,20); R2(A,B,BUF,12); \
    WKA2(4,C,D); C2(C,D,22); R2(C,D,BUF,13); \
    WKA2(4,A,B); C2(A,B,24); R2(A,B,BUF,14); \
    WKA2(4,C,D); C2(C,D,26); R2(C,D,BUF,15); \
    WKA2(4,A,B); C2(A,B,28); \
    WKA2(0,C,D); C2(C,D,30); \
    BAR; \
  } while (0)

  BAR;   // prologue: wait for wave1's stage(0)+G(0)
  #pragma unroll 1
  for (int cp = 0; cp < NCH / 2; ++cp) {
    CHUNK(0);
    CHUNK(1);
  }

  {
    float* sp = Sfin + (size_t)bh * 1024 + (rg * 4 + il) * 32 + p * 2;
    sp[0] = S2.x; sp[1] = S2.y;
  }
#undef C2
#undef R2
#undef WKA2
#undef CHUNK
}

// ---------------------------------------------------------------- rmsnorm * silu(gate) -> bf16
__global__ void __launch_bounds__(256) rms_silu(
    const float* __restrict__ ctx, const float* __restrict__ gate,
    const float* __restrict__ norm_w, unsigned short* __restrict__ ctx2)
{
  size_t row = (size_t)blockIdx.x * 4 + (threadIdx.x >> 6);
  int lane = threadIdx.x & 63;
  const float4 x = *(const float4*)&ctx[row * SD + lane * 4];
  float s = x.x * x.x + x.y * x.y + x.z * x.z + x.w * x.w;
  #pragma unroll
  for (int m = 32; m >= 1; m >>= 1) s += __shfl_xor(s, m, 64);
  float rs = 1.0f / sqrtf(s * (1.0f / 256.0f) + 1e-6f);
  const float4 g = *(const float4*)&gate[row * SD + lane * 4];
  const float4 w = *(const float4*)&norm_w[lane * 4];
  ushort4 o;
  o.x = f2bf(x.x * rs * w.x * (g.x / (1.0f + expf(-g.x))));
  o.y = f2bf(x.y * rs * w.y * (g.y / (1.0f + expf(-g.y))));
  o.z = f2bf(x.z * rs * w.z * (g.z / (1.0f + expf(-g.z))));
  o.w = f2bf(x.w * rs * w.w * (g.w / (1.0f + expf(-g.w))));
  *(ushort4*)&ctx2[row * SD + lane * 4] = o;
}

// ---------------------------------------------------------------- output GEMM
__global__ void __launch_bounds__(256) out_gemm(
    const unsigned short* __restrict__ ctx2, const unsigned short* __restrict__ Wob,
    float* __restrict__ out)
{
  __shared__ unsigned short Asm[PM*PK];
  __shared__ unsigned short Bsm[PN*PK];
  const int t = threadIdx.x;
  const int w = t >> 6, lane = t & 63;
  const int bm0 = blockIdx.x * PM;
  const int bn0 = blockIdx.y * PN;

  f32x4 acc[2][4];
  #pragma unroll
  for (int i = 0; i < 2; ++i)
    #pragma unroll
    for (int j = 0; j < 4; ++j) acc[i][j] = (f32x4){0.f, 0.f, 0.f, 0.f};

  for (int k0 = 0; k0 < SD; k0 += PK) {
    #pragma unroll
    for (int it = 0; it < 4; ++it) {
      int unit = t + it * 256;
      int row = unit >> 3, seg = unit & 7;
      int dseg = seg ^ (row & 7);
      const unsigned short* g = ctx2 + (size_t)(bm0 + row) * SD + k0 + dseg * 8;
      gload16(g, (char*)Asm + (w * 1024 + it * 4096));
    }
    #pragma unroll
    for (int it = 0; it < 2; ++it) {
      int unit = t + it * 256;
      int n = unit >> 3, seg = unit & 7;
      int dseg = seg ^ (n & 7);
      const unsigned short* g = Wob + (size_t)(bn0 + n) * SD + k0 + dseg * 8;
      gload16(g, (char*)Bsm + (w * 1024 + it * 4096));
    }
    __syncthreads();
    #pragma unroll
    for (int ks = 0; ks < 2; ++ks) {
      short8 af[2], bfr[4];
      int u = ks * 4 + (lane >> 4);
      int slot = u ^ (lane & 7);
      #pragma unroll
      for (int rb = 0; rb < 2; ++rb) {
        int row = w * 32 + rb * 16 + (lane & 15);
        af[rb] = *(const short8*)((const char*)Asm + row * 128 + slot * 16);
      }
      #pragma unroll
      for (int cb = 0; cb < 4; ++cb) {
        int nn = cb * 16 + (lane & 15);
        bfr[cb] = *(const short8*)((const char*)Bsm + nn * 128 + slot * 16);
      }
      #pragma unroll
      for (int rb = 0; rb < 2; ++rb)
        #pragma unroll
        for (int cb = 0; cb < 4; ++cb)
          acc[rb][cb] = __builtin_amdgcn_mfma_f32_16x16x32_bf16(af[rb], bfr[cb], acc[rb][cb], 0, 0, 0);
    }
    __syncthreads();
  }
  #pragma unroll
  for (int rb = 0; rb < 2; ++rb)
    #pragma unroll
    for (int cb = 0; cb < 4; ++cb) {
      int n = bn0 + cb * 16 + (lane & 15);
      #pragma unroll
      for (int r = 0; r < 4; ++r) {
        int m = bm0 + w * 32 + rb * 16 + (lane >> 4) * 4 + r;
        out[(size_t)m * 512 + n] = acc[rb][cb][r];
      }
    }
}

// ---------------------------------------------------------------- launcher
// ws layout (bytes), total 253,493,248:
//   hb   bf16 [32768][512]            @ 0
//   Wc   bf16 [1536][512]             @ 33,554,432
//   Wob  bf16 [512][256]              @ 35,127,296
//   KQi  f32  [64][4096][64]          @ 35,389,440   (16 groups x [k2, q2])
//   AVB  f32x4 [64][4096][32]         @ 102,498,304  (a, v, beta, pad/G)
//   ctx2 bf16 [32768][256]            @ 236,716,032
// d_out reuse: ctx f32 [32768][256] @ 0; gate f32 [32768][256] @ +8388608 floats
// (both overwritten later by out_gemm); Sfin @ +16777216 floats.
extern "C" void kernel_launch(void* const* d_in, const int* in_sizes, int n_in,
                              void* d_out, int out_size, void* d_ws, size_t ws_size,
                              hipStream_t stream) {
  (void)in_sizes; (void)n_in; (void)out_size; (void)ws_size;
  const float* hidden  = (const float*)d_in[0];
  const float* state   = (const float*)d_in[1];
  const float* W_k     = (const float*)d_in[2];
  const float* W_v     = (const float*)d_in[3];
  const float* W_q     = (const float*)d_in[4];
  const float* W_beta  = (const float*)d_in[5];
  const float* b_beta  = (const float*)d_in[6];
  const float* W_alpha = (const float*)d_in[7];
  const float* b_alpha = (const float*)d_in[8];
  const float* W_out   = (const float*)d_in[9];
  const float* gate_W  = (const float*)d_in[10];
  const float* norm_w  = (const float*)d_in[11];
  float* out = (float*)d_out;

  char* ws = (char*)d_ws;
  unsigned short* hb  = (unsigned short*)(ws);
  unsigned short* Wc  = (unsigned short*)(ws + 33554432);
  unsigned short* Wob = (unsigned short*)(ws + 35127296);
  float* KQi  = (float*)(ws + 35389440);
  float* AVBf = (float*)(ws + 102498304);
  unsigned short* ctx2 = (unsigned short*)(ws + 236716032);
  float* ctx  = out;                 // fp32 scratch, overwritten by out_gemm
  float* gate = out + 8388608;       // fp32 scratch, overwritten by out_gemm
  float* Sfin = out + 16777216;      // final state output

  cvt_f32_bf16<<<2048, 256, 0, stream>>>(hidden, hb, M_TOK * HID / 4);
  cvt_weights<<<dim3(128, 7), 256, 0, stream>>>(W_k, W_v, W_q, W_beta, W_alpha, gate_W, W_out, Wc, Wob);

  proj_gemm<<<dim3(256, 8), 256, 0, stream>>>(hb, Wc, b_beta, b_alpha, KQi, AVBf, gate);
  scan_kernel<<<512, 128, 0, stream>>>(KQi, (const float4*)AVBf, state, ctx, Sfin);
  rms_silu<<<8192, 256, 0, stream>>>(ctx, gate, norm_w, ctx2);
  out_gemm<<<dim3(256, 8), 256, 0, stream>>>(ctx2, Wob, out);
}